// Round 4
// baseline (1766.838 us; speedup 1.0000x reference)
//
#include <hip/hip_runtime.h>
#include <math.h>

#define T_LEN 20000
#define KST 64
#define KP1 65
#define DD 32
#define CHK 250
#define LCH 80
#define GSZ 10
#define NG 25
#define OPS 4296   // operator record stride in floats: 4225 vals + 65 sig + 3 mask + pad

static __device__ __forceinline__ float wsum64(float v){
  v += __shfl_xor(v, 1);  v += __shfl_xor(v, 2);  v += __shfl_xor(v, 4);
  v += __shfl_xor(v, 8);  v += __shfl_xor(v, 16); v += __shfl_xor(v, 32);
  return v;
}
static __device__ __forceinline__ float wmax64(float v){
  v = fmaxf(v, __shfl_xor(v, 1));  v = fmaxf(v, __shfl_xor(v, 2));  v = fmaxf(v, __shfl_xor(v, 4));
  v = fmaxf(v, __shfl_xor(v, 8));  v = fmaxf(v, __shfl_xor(v, 16)); v = fmaxf(v, __shfl_xor(v, 32));
  return v;
}
static __device__ __forceinline__ float readlane_f(float v, int i){
  return __int_as_float(__builtin_amdgcn_readlane(__float_as_int(v), i));
}
static __device__ __forceinline__ float digamma_f(float x){
  float r = 0.f;
  while (x < 6.f){ r -= 1.f / x; x += 1.f; }
  float xi = 1.f / x;
  float xi2 = xi * xi;
  return r + logf(x) - 0.5f * xi
       - xi2 * (0.08333333333f - xi2 * (0.008333333333f - xi2 * 0.003968253968f));
}
static __device__ __forceinline__ float rcp_nr(float s){
  float r = __builtin_amdgcn_rcpf(s);
  return r * (2.0f - s * r);
}

// ---------------- per-component prep: Cholesky, inverse, E_logdet ----------------
__global__ void prep_k(const float* __restrict__ mu, const float* __restrict__ kappa,
                       const float* __restrict__ nu, const float* __restrict__ Psi,
                       float* __restrict__ Lam, float* __restrict__ dLam,
                       float* __restrict__ constk){
  const int k = blockIdx.x, tid = threadIdx.x;
  __shared__ float P[DD][DD + 1];
  const float* Pk = Psi + k * DD * DD;
  for (int e = tid; e < DD * DD; e += 64) P[e / DD][e % DD] = Pk[e];
  __syncthreads();
  for (int c = 0; c < DD; ++c){
    if (tid == c){
      float s = P[c][c];
      for (int m = 0; m < c; ++m) s -= P[c][m] * P[c][m];
      P[c][c] = sqrtf(s);
    }
    __syncthreads();
    if (tid > c && tid < DD){
      float s = P[tid][c];
      for (int m = 0; m < c; ++m) s -= P[tid][m] * P[c][m];
      P[tid][c] = s / P[c][c];
    }
    __syncthreads();
  }
  const float nuk = nu[k];
  if (tid < DD){
    float y[DD];
    #pragma unroll
    for (int r2 = 0; r2 < DD; ++r2){
      float s = (r2 == tid) ? 1.f : 0.f;
      #pragma unroll
      for (int m = 0; m < r2; ++m) s -= P[r2][m] * y[m];
      y[r2] = s / P[r2][r2];
    }
    #pragma unroll
    for (int r2 = DD - 1; r2 >= 0; --r2){
      float s = y[r2];
      #pragma unroll
      for (int m = r2 + 1; m < DD; ++m) s -= P[m][r2] * y[m];
      y[r2] = s / P[r2][r2];
    }
    #pragma unroll
    for (int i = 0; i < DD; ++i) Lam[k * DD * DD + i * DD + tid] = nuk * y[i];
    dLam[k * DD + tid] = nuk * y[tid];
  }
  float dg = 0.f, ld = 0.f;
  if (tid < DD){
    dg = digamma_f((nuk + 1.f - (float)(tid + 1)) * 0.5f);
    ld = logf(P[tid][tid]);
  }
  dg = wsum64(dg);
  ld = wsum64(ld);
  if (tid == 0){
    const float LOG2 = 0.6931471805599453f, LOG2PI = 1.8378770664093453f;
    float logdet = 2.f * ld;
    float Elogdet = dg - DD * LOG2 - logdet;
    float t3 = DD * nuk / (kappa[k] * fmaxf(nuk - DD - 1.f, 1.f));
    constk[k] = -0.5f * (Elogdet + t3 + DD * LOG2PI);
  }
}

// ---------------- transition prep ----------------
__global__ void prep_trans(const float* __restrict__ phi, const float* __restrict__ pi_star,
                           float* __restrict__ M_mat, float* __restrict__ MT,
                           float* __restrict__ logA, float* __restrict__ logpi){
  const int i = threadIdx.x;  // 64 rows
  float rs = 0.f;
  for (int j = 0; j < KP1; ++j) rs += phi[i * KP1 + j];
  float dgs = digamma_f(rs);
  for (int j = 0; j < KP1; ++j){
    float la = digamma_f(phi[i * KP1 + j]) - dgs;
    logA[i * KP1 + j] = la;
    float e = expf(la);
    M_mat[i * 68 + j] = e;
    MT[j * 68 + i] = e;
  }
  if (i == 0){
    for (int j = 0; j < KP1; ++j){
      float pe = pi_star[j] + 1e-9f;
      logpi[j] = logf(pe);
      M_mat[64 * 68 + j] = pe;
      MT[j * 68 + 64] = pe;
    }
  }
}

// ---------------- emission log-likelihoods ----------------
__global__ void logb_k(const float* __restrict__ zmu, const float* __restrict__ zvar,
                       const float* __restrict__ mu, const float* __restrict__ Lam,
                       const float* __restrict__ dLam, const float* __restrict__ constk,
                       float* __restrict__ logB){
  const int k = blockIdx.y, tid = threadIdx.x;
  const int t = blockIdx.x * 256 + tid;
  __shared__ float Ls[DD * DD];
  __shared__ float mus[DD], dls[DD];
  for (int e = tid; e < DD * DD; e += 256) Ls[e] = Lam[k * DD * DD + e];
  if (tid < DD){ mus[tid] = mu[k * DD + tid]; dls[tid] = dLam[k * DD + tid]; }
  __syncthreads();
  if (t >= T_LEN) return;
  const float4* zm4 = reinterpret_cast<const float4*>(zmu + (size_t)t * DD);
  const float4* zv4 = reinterpret_cast<const float4*>(zvar + (size_t)t * DD);
  float d[DD];
  float acc1 = 0.f;
  #pragma unroll
  for (int q = 0; q < DD / 4; ++q){
    float4 vm = zm4[q]; float4 vv = zv4[q];
    d[4*q+0] = vm.x - mus[4*q+0];
    d[4*q+1] = vm.y - mus[4*q+1];
    d[4*q+2] = vm.z - mus[4*q+2];
    d[4*q+3] = vm.w - mus[4*q+3];
    acc1 = fmaf(dls[4*q+0], vv.x, acc1);
    acc1 = fmaf(dls[4*q+1], vv.y, acc1);
    acc1 = fmaf(dls[4*q+2], vv.z, acc1);
    acc1 = fmaf(dls[4*q+3], vv.w, acc1);
  }
  float acc2 = 0.f;
  #pragma unroll
  for (int i = 0; i < DD; ++i){
    float s = 0.f;
    #pragma unroll
    for (int q = 0; q < DD/4; ++q){
      float4 L4 = *reinterpret_cast<const float4*>(&Ls[i*DD + q*4]);
      s = fmaf(L4.x, d[q*4+0], s);
      s = fmaf(L4.y, d[q*4+1], s);
      s = fmaf(L4.z, d[q*4+2], s);
      s = fmaf(L4.w, d[q*4+3], s);
    }
    acc2 = fmaf(s, d[i], acc2);
  }
  logB[(size_t)t * KP1 + k] = constk[k] - 0.5f * (acc1 + acc2);
}

// ---------------- Bexp = exp(logB - rowmax) ----------------
__global__ void bexp_k(const float* __restrict__ logB, float* __restrict__ Bexp,
                       float* __restrict__ bmax){
  const int lane = threadIdx.x & 63, w = threadIdx.x >> 6;
  const int t = blockIdx.x * 4 + w;
  if (t >= T_LEN) return;
  float v = logB[(size_t)t * KP1 + lane];
  float v64 = logB[(size_t)t * KP1 + 64];
  float m = fmaxf(wmax64(v), v64);
  Bexp[(size_t)t * KP1 + lane] = expf(v - m);
  if (lane == 0){ Bexp[(size_t)t * KP1 + 64] = expf(v64 - m); bmax[t] = m; }
}

// ---------------- phase 1: per-chunk operators (row-sparse) ----------------
__global__ __launch_bounds__(64) void p1_k(const float* __restrict__ MT_g,
    const float* __restrict__ Bexp, float* __restrict__ S){
  __shared__ float MTl[65 * 68];
  __shared__ float Xbuf[2][65][64];
  const int lane = threadIdx.x;
  const int dir = blockIdx.y;
  for (int e = lane; e < 65 * 68; e += 64) MTl[e] = MT_g[e];
  __syncthreads();
  const int bx = blockIdx.x;
  const bool service = bx >= CHK;
  const int c = service ? bx - CHK : bx;
  int r0, r1;
  if (dir == 0){ r0 = 1 + c * LCH; r1 = min((c + 1) * LCH, T_LEN - 1); }
  else {
    int ue = min((c + 1) * LCH, T_LEN - 1) - 1;
    r0 = (T_LEN - 1) - ue; r1 = (T_LEN - 1) - c * LCH;
  }
  float* Sc = S + (size_t)(dir * CHK + c) * OPS;
  float* sig_out = Sc + 4225;

  if (!service){
    float rs = 1.f, sig = 0.f;
    unsigned long long pmask = 0; bool pb64 = false;
    unsigned long long dirty0 = ~0ull, dirty1 = ~0ull;
    bool dirty64_0 = true, dirty64_1 = true;
    int cur = 0;
    float bv0 = Bexp[(size_t)r0 * KP1 + lane];
    float b640 = Bexp[(size_t)r0 * KP1 + 64];
    float bv1 = 0.f, b641 = 0.f;
    if (r0 + 1 <= r1){ bv1 = Bexp[(size_t)(r0+1) * KP1 + lane]; b641 = Bexp[(size_t)(r0+1) * KP1 + 64]; }
    for (int r = r0; r <= r1; ++r){
      float bv2 = 0.f, b642 = 0.f;
      if (r + 2 <= r1){ bv2 = Bexp[(size_t)(r+2) * KP1 + lane]; b642 = Bexp[(size_t)(r+2) * KP1 + 64]; }
      unsigned long long nmask = __ballot(bv0 != 0.f);
      bool nb64 = (b640 != 0.f);
      const int nb = cur ^ 1;
      float cmax = 0.f;
      if (r == r0){
        unsigned long long m = nmask;
        while (m){
          int i = __builtin_ctzll(m); m &= m - 1;
          float nv = readlane_f(bv0, i) * MTl[i*68 + lane];
          Xbuf[nb][i][lane] = nv; cmax = fmaxf(cmax, nv);
        }
        if (nb64){
          float nv = b640 * MTl[64*68 + lane];
          Xbuf[nb][64][lane] = nv; cmax = fmaxf(cmax, nv);
        }
      } else {
        const bool dense = __builtin_popcountll(pmask) >= 24;
        for (int pass = 0; pass < 2; ++pass){
          if (pass == 1 && !nb64) break;
          unsigned long long mm = (pass == 0) ? nmask : 1ull;
          while (mm){
            int i;
            if (pass == 0){ i = __builtin_ctzll(mm); mm &= mm - 1; }
            else { i = 64; mm = 0; }
            float acc = 0.f;
            if (dense){
              #pragma unroll
              for (int g4 = 0; g4 < 16; ++g4){
                float4 m4 = *reinterpret_cast<const float4*>(&MTl[i*68 + 4*g4]);
                acc = fmaf(m4.x, Xbuf[cur][4*g4+0][lane], acc);
                acc = fmaf(m4.y, Xbuf[cur][4*g4+1][lane], acc);
                acc = fmaf(m4.z, Xbuf[cur][4*g4+2][lane], acc);
                acc = fmaf(m4.w, Xbuf[cur][4*g4+3][lane], acc);
              }
              acc = fmaf(MTl[i*68 + 64], Xbuf[cur][64][lane], acc);
            } else {
              unsigned long long jm = pmask;
              while (jm){
                int j = __builtin_ctzll(jm); jm &= jm - 1;
                acc = fmaf(MTl[i*68 + j], Xbuf[cur][j][lane], acc);
              }
              if (pb64) acc = fmaf(MTl[i*68 + 64], Xbuf[cur][64][lane], acc);
            }
            float bi = (i == 64) ? b640 : readlane_f(bv0, i);
            float nv = bi * acc * rs;
            Xbuf[nb][i][lane] = nv;
            cmax = fmaxf(cmax, nv);
          }
        }
      }
      {
        unsigned long long dN = (nb == 0) ? dirty0 : dirty1;
        bool d64N = (nb == 0) ? dirty64_0 : dirty64_1;
        unsigned long long zm = dN & ~nmask;
        while (zm){
          int z = __builtin_ctzll(zm); zm &= zm - 1;
          Xbuf[nb][z][lane] = 0.f;
        }
        if (d64N && !nb64) Xbuf[nb][64][lane] = 0.f;
        if (nb == 0){ dirty0 = nmask; dirty64_0 = nb64; }
        else        { dirty1 = nmask; dirty64_1 = nb64; }
      }
      float s = fmaxf(wmax64(cmax), 1e-37f);
      sig += logf(s);
      rs = 1.f / s;
      pmask = nmask; pb64 = nb64;
      cur = nb;
      bv0 = bv1; b640 = b641; bv1 = bv2; b641 = b642;
    }
    for (int i = 0; i < 65; ++i){
      bool act = (i < 64) ? ((pmask >> i) & 1ull) : pb64;
      float v = act ? Xbuf[cur][i][lane] * rs : 0.f;
      Sc[i * 65 + lane] = v;
    }
    sig_out[lane] = sig;
    if (lane == 0){
      unsigned int* mw = (unsigned int*)Sc;
      mw[4290] = (unsigned int)(pmask & 0xffffffffull);
      mw[4291] = (unsigned int)(pmask >> 32);
      mw[4292] = pb64 ? 1u : 0u;
    }
  } else {
    float v = 0.f, v64 = 1.f, sig = 0.f;
    float bvec = Bexp[(size_t)r0 * KP1 + lane];
    float b64  = Bexp[(size_t)r0 * KP1 + 64];
    for (int r = r0; r <= r1; ++r){
      float bvn = 0.f, b64n = 0.f;
      if (r < r1){
        bvn  = Bexp[(size_t)(r + 1) * KP1 + lane];
        b64n = Bexp[(size_t)(r + 1) * KP1 + 64];
      }
      unsigned long long mask = __ballot(bvec != 0.f);
      float vn = 0.f, v64n = 0.f;
      while (mask){
        int i = __builtin_ctzll(mask); mask &= mask - 1;
        float mi = MTl[i * 68 + lane];
        float t = mi * v;
        float sum = wsum64(t) + MTl[i * 68 + 64] * v64;
        float bi = readlane_f(bvec, i);
        vn = (lane == i) ? bi * sum : vn;
      }
      if (b64 != 0.f){
        float t = MTl[64 * 68 + lane] * v;
        float sum = wsum64(t) + MTl[64 * 68 + 64] * v64;
        v64n = b64 * sum;
      }
      float m = wmax64(vn);
      m = fmaxf(m, v64n);
      m = fmaxf(m, 1e-37f);
      float irs = 1.f / m;
      v = vn * irs; v64 = v64n * irs;
      sig += logf(m);
      bvec = bvn; b64 = b64n;
    }
    Sc[lane * 65 + 64] = v;
    if (lane == 0){ Sc[64 * 65 + 64] = v64; sig_out[64] = sig; }
  }
}

// ---------------- phase 2a: compose chunk ops into NG group ops ----------------
// dir=0: G = C_last ... C_first, stored direct (apply: v' = G.(v .* exp(sig))).
// dir=1: store Ht with Ht := X_cc^T . D~_cc . Ht, init Ht = X_first^T.
//        Application of Ht records is ALSO forward-style (uniform p2b code).
__global__ __launch_bounds__(256) void p2a_k(const float* __restrict__ S,
    float* __restrict__ Gop){
  const int tid = threadIdx.x, lane = tid & 63, wv = tid >> 6;
  const int g = blockIdx.x, dir = blockIdx.y;
  __shared__ float Ys[65 * 65];
  __shared__ float Gt[65 * 65];
  __shared__ float Scl[OPS];
  __shared__ float ysig[65];
  __shared__ unsigned int msh[3];
  const float* base = S + (size_t)(dir * CHK + g * GSZ) * OPS;
  if (dir == 0){
    for (int e = tid; e < 4225; e += 256) Ys[e] = base[e];
  } else {
    for (int e = tid; e < 4225; e += 256){
      int i = e / 65, j = e - i * 65;
      Ys[j * 65 + i] = base[e];       // transposed init: Ht = X_first^T
    }
  }
  if (tid < 65) ysig[tid] = base[4225 + tid];
  if (tid < 3) msh[tid] = ((const unsigned int*)base)[4290 + tid];
  __syncthreads();
  for (int cc = 1; cc < GSZ; ++cc){
    const float* opc = base + (size_t)cc * OPS;
    for (int e = tid; e < OPS; e += 256) Scl[e] = opc[e];
    __syncthreads();
    if (wv == 0){
      float sigm = Scl[4225 + 0];
      float sigs = Scl[4225 + 64];
      float smc = fmaxf(sigm, sigs);
      float rfm = expf(sigm - smc), rfs = expf(sigs - smc);
      if (dir == 0){
        unsigned long long pm = (unsigned long long)msh[0] | ((unsigned long long)msh[1] << 32);
        bool pb64 = (msh[2] & 1u) != 0;
        const unsigned int* smw = (const unsigned int*)Scl;
        unsigned long long im = (unsigned long long)smw[4290] | ((unsigned long long)smw[4291] << 32);
        bool ib64 = (smw[4292] & 1u) != 0;
        const bool dense = __builtin_popcountll(pm) >= 24;
        float colmax = 0.f, col64max = 0.f;
        for (int i = 0; i < 65; ++i){
          bool act = (i < 64) ? ((im >> i) & 1ull) : ib64;
          float acc = 0.f, acc64 = 0.f;
          if (act){
            if (dense){
              for (int k = 0; k < 64; ++k)
                acc = fmaf(Scl[i*65 + k], Ys[k*65 + lane], acc);
              acc *= rfm;
            } else {
              unsigned long long jm = pm;
              while (jm){
                int k = __builtin_ctzll(jm); jm &= jm - 1;
                acc = fmaf(Scl[i*65 + k], Ys[k*65 + lane], acc);
              }
              acc *= rfm;
            }
            if (pb64) acc = fmaf(rfs * Scl[i*65 + 64], Ys[64*65 + lane], acc);
            float part = rfm * Scl[i*65 + lane] * Ys[lane*65 + 64];
            acc64 = wsum64(part);
            if (pb64) acc64 += rfs * Scl[i*65 + 64] * Ys[64*65 + 64];
          }
          Gt[i*65 + lane] = acc;
          if (lane == 0) Gt[i*65 + 64] = acc64;
          colmax = fmaxf(colmax, acc);
          col64max = fmaxf(col64max, acc64);
        }
        float mj = fmaxf(colmax, 1e-37f);
        float inv = 1.f / mj;
        for (int i = 0; i < 65; ++i) Ys[i*65 + lane] = Gt[i*65 + lane] * inv;
        ysig[lane] += logf(mj) + smc;
        if (lane == 0){
          float m64 = fmaxf(col64max, 1e-37f);
          float i64 = 1.f / m64;
          for (int i = 0; i < 65; ++i) Ys[i*65 + 64] = Gt[i*65 + 64] * i64;
          ysig[64] += logf(m64) + smc;
          msh[0] = (unsigned int)(im & 0xffffffffull);
          msh[1] = (unsigned int)(im >> 32);
          msh[2] = ib64 ? 1u : 0u;
        }
      } else {
        // Ht_new[i][col] = sum_k X_cc[k][i]*w_k*Ht[k][col], w_k = rfm (k<64) / rfs (k=64)
        float colmax = 0.f, col64max = 0.f;
        for (int i = 0; i < 65; ++i){
          float acc = 0.f;
          for (int k = 0; k < 64; ++k)
            acc = fmaf(Scl[k*65 + i], Ys[k*65 + lane], acc);
          acc *= rfm;
          acc = fmaf(rfs * Scl[64*65 + i], Ys[64*65 + lane], acc);
          float part = rfm * Scl[lane*65 + i] * Ys[lane*65 + 64];
          float acc64 = wsum64(part) + rfs * Scl[64*65 + i] * Ys[64*65 + 64];
          Gt[i*65 + lane] = acc;
          if (lane == 0) Gt[i*65 + 64] = acc64;
          colmax = fmaxf(colmax, acc);
          col64max = fmaxf(col64max, acc64);
        }
        float mj = fmaxf(colmax, 1e-37f);
        float inv = 1.f / mj;
        for (int i = 0; i < 65; ++i) Ys[i*65 + lane] = Gt[i*65 + lane] * inv;
        ysig[lane] += logf(mj) + smc;
        if (lane == 0){
          float m64 = fmaxf(col64max, 1e-37f);
          float i64 = 1.f / m64;
          for (int i = 0; i < 65; ++i) Ys[i*65 + 64] = Gt[i*65 + 64] * i64;
          ysig[64] += logf(m64) + smc;
        }
      }
    }
    __syncthreads();
  }
  float* outp = Gop + (size_t)(dir * NG + g) * OPS;
  for (int e = tid; e < 4225; e += 256) outp[e] = Ys[e];
  if (tid < 65) outp[4225 + tid] = ysig[tid];
  if (tid < 3) ((unsigned int*)outp)[4290 + tid] = msh[tid];
}

// ---------------- phase 2b: sequential over NG group ops (2 blocks) ----------------
// uniform forward-style application (dir=1 records are stored as Ht)
__global__ __launch_bounds__(256) void p2b_k(const float* __restrict__ Gop,
    const float* __restrict__ M_mat, const float* __restrict__ Bexp,
    float* __restrict__ gseed){
  const int dir = blockIdx.x, tid = threadIdx.x;
  __shared__ float Sl[OPS];
  __shared__ float vl[66];
  __shared__ float red[2];
  if (dir == 0){ if (tid < 65) vl[tid] = M_mat[64*68 + tid] * Bexp[tid]; }
  else { if (tid < 65) vl[tid] = 1.f; }
  __syncthreads();
  if (tid < 64){
    float x = vl[tid];
    float s = wsum64(x) + vl[64];
    if (tid == 0) red[0] = 1.f / fmaxf(s, 1e-37f);
  }
  __syncthreads();
  if (tid < 65) vl[tid] *= red[0];
  const float* Gg = Gop + (size_t)dir * NG * OPS;
  float sb[17];
  #pragma unroll
  for (int u = 0; u < 17; ++u){ int e = tid + 256*u; sb[u] = (e < OPS) ? Gg[e] : 0.f; }
  for (int c = 0; c < NG; ++c){
    __syncthreads();
    #pragma unroll
    for (int u = 0; u < 17; ++u){ int e = tid + 256*u; if (e < OPS) Sl[e] = sb[u]; }
    __syncthreads();
    if (c + 1 < NG){
      const float* Sn = Gg + (size_t)(c+1) * OPS;
      #pragma unroll
      for (int u = 0; u < 17; ++u){ int e = tid + 256*u; sb[u] = (e < OPS) ? Sn[e] : 0.f; }
    }
    if (tid < 65) gseed[(size_t)(dir * NG + c) * KP1 + tid] = vl[tid];
    if (tid < 64){
      float gm = wmax64(Sl[4225 + tid]);
      if (tid == 0) red[1] = fmaxf(gm, Sl[4225 + 64]);
    }
    __syncthreads();
    if (tid < 65) vl[tid] = vl[tid] * expf(Sl[4225 + tid] - red[1]);
    __syncthreads();
    float vn = 0.f;
    if (tid < 65){
      for (int j = 0; j < 65; ++j) vn = fmaf(Sl[tid*65 + j], vl[j], vn);
    }
    __syncthreads();
    if (tid < 65) vl[tid] = vn;
    __syncthreads();
    if (tid < 64){
      float x = vl[tid];
      float s = wsum64(x) + vl[64];
      if (tid == 0) red[0] = 1.f / fmaxf(s, 1e-37f);
    }
    __syncthreads();
    if (tid < 65) vl[tid] *= red[0];
  }
}

// ---------------- phase 2c: per-group chunk-seed derivation ----------------
// applies CHUNK records (X orientation): dir=0 direct matvec, dir=1 transposed.
__global__ __launch_bounds__(256) void p2c_k(const float* __restrict__ S,
    const float* __restrict__ gseed, float* __restrict__ vstore){
  const int g = blockIdx.x, dir = blockIdx.y, tid = threadIdx.x;
  __shared__ float Sl[OPS];
  __shared__ float vl[66];
  __shared__ float red[2];
  if (tid < 65) vl[tid] = gseed[(size_t)(dir * NG + g) * KP1 + tid];
  const float* base = S + (size_t)(dir * CHK + g * GSZ) * OPS;
  float sb[17];
  #pragma unroll
  for (int u = 0; u < 17; ++u){ int e = tid + 256*u; sb[u] = (e < OPS) ? base[e] : 0.f; }
  for (int cc = 0; cc < GSZ; ++cc){
    __syncthreads();
    #pragma unroll
    for (int u = 0; u < 17; ++u){ int e = tid + 256*u; if (e < OPS) Sl[e] = sb[u]; }
    __syncthreads();
    if (cc + 1 < GSZ){
      const float* Sn = base + (size_t)(cc+1) * OPS;
      #pragma unroll
      for (int u = 0; u < 17; ++u){ int e = tid + 256*u; sb[u] = (e < OPS) ? Sn[e] : 0.f; }
    }
    const int cid = g * GSZ + cc;
    if (tid < 65) vstore[(size_t)(dir * CHK + cid) * KP1 + tid] = vl[tid];
    if (tid < 64){
      float gm = wmax64(Sl[4225 + tid]);
      if (tid == 0) red[1] = fmaxf(gm, Sl[4225 + 64]);
    }
    __syncthreads();
    if (tid < 65) vl[tid] = vl[tid] * expf(Sl[4225 + tid] - red[1]);
    __syncthreads();
    float vn = 0.f;
    if (tid < 65){
      if (dir == 0){
        for (int j = 0; j < 65; ++j) vn = fmaf(Sl[tid*65 + j], vl[j], vn);
      } else {
        for (int k = 0; k < 65; ++k) vn = fmaf(Sl[k*65 + tid], vl[k], vn);
      }
    }
    __syncthreads();
    if (tid < 65) vl[tid] = vn;
    __syncthreads();
    if (tid < 64){
      float x = vl[tid];
      float s = wsum64(x) + vl[64];
      if (tid == 0) red[0] = 1.f / fmaxf(s, 1e-37f);
    }
    __syncthreads();
    if (tid < 65) vl[tid] *= red[0];
  }
}

// ---------------- phase 3: exact per-chunk normalized p/q ----------------
__global__ __launch_bounds__(64) void p3_k(const float* __restrict__ M_mat,
    const float* __restrict__ MT_g, const float* __restrict__ Bexp,
    const float* __restrict__ bmax, const float* __restrict__ vstore,
    float* __restrict__ pstore, float* __restrict__ qstore,
    float* __restrict__ cfor, float* __restrict__ csum){
  __shared__ float Ml[65 * 68];
  const int lane = threadIdx.x;
  const int c = blockIdx.x, dir = blockIdx.y;
  const float* src = (dir == 0) ? M_mat : MT_g;
  for (int e = lane; e < 65 * 68; e += 64) Ml[e] = src[e];
  __syncthreads();
  if (dir == 0){
    float p, p64, sig;
    const int r0 = 1 + c * LCH, r1 = min((c + 1) * LCH, T_LEN - 1);
    if (c == 0){
      float pe = Ml[64 * 68 + lane], pe64 = Ml[64 * 68 + 64];
      float b = Bexp[lane], b64v = Bexp[64];
      float val = pe * b, v64 = pe64 * b64v;
      float s = wsum64(val) + v64;
      float rr = 1.f / fmaxf(s, 1e-37f);
      p = val * rr; p64 = v64 * rr;
      pstore[lane] = p; if (lane == 0) pstore[64] = p64;
      sig = logf(fmaxf(s, 1e-37f)) + bmax[0];
      if (lane == 0) cfor[0] = sig;
    } else {
      p = vstore[(size_t)c * KP1 + lane];
      p64 = vstore[(size_t)c * KP1 + 64];
      sig = 0.f;
    }
    float bvec = Bexp[(size_t)r0 * KP1 + lane], b64 = Bexp[(size_t)r0 * KP1 + 64];
    for (int r = r0; r <= r1; ++r){
      float bvn = 0.f, b64n = 0.f;
      if (r < r1){
        bvn = Bexp[(size_t)(r + 1) * KP1 + lane]; b64n = Bexp[(size_t)(r + 1) * KP1 + 64];
      }
      unsigned long long mask = __ballot(p != 0.f);
      float msg = 0.f, msg64 = 0.f;
      while (mask){
        int i = __builtin_ctzll(mask); mask &= mask - 1;
        float pi_ = readlane_f(p, i);
        msg   = fmaf(pi_, Ml[i * 68 + lane], msg);
        msg64 = fmaf(pi_, Ml[i * 68 + 64], msg64);
      }
      if (p64 != 0.f){
        msg   = fmaf(p64, Ml[64 * 68 + lane], msg);
        msg64 = fmaf(p64, Ml[64 * 68 + 64], msg64);
      }
      float val = bvec * msg, v64 = b64 * msg64;
      float s = wsum64(val) + v64;
      float rr = 1.f / fmaxf(s, 1e-37f);
      p = val * rr; p64 = v64 * rr;
      pstore[(size_t)r * KP1 + lane] = p;
      if (lane == 0) pstore[(size_t)r * KP1 + 64] = p64;
      sig += logf(fmaxf(s, 1e-37f)) + bmax[r];
      if (lane == 0) cfor[r] = sig;
      bvec = bvn; b64 = b64n;
    }
    if (lane == 0) csum[c] = sig;
  } else {
    float q, q64;
    const int ustart = c * LCH;
    const int ue = min((c + 1) * LCH, T_LEN - 1) - 1;
    if (c == 0){
      q = 1.f / 65.f; q64 = 1.f / 65.f;
      qstore[(size_t)(T_LEN - 1) * KP1 + lane] = q;
      if (lane == 0) qstore[(size_t)(T_LEN - 1) * KP1 + 64] = q64;
    } else {
      q = vstore[(size_t)(CHK + c) * KP1 + lane];
      q64 = vstore[(size_t)(CHK + c) * KP1 + 64];
    }
    int rfirst = (T_LEN - 1) - ustart;
    float bvec = Bexp[(size_t)rfirst * KP1 + lane], b64 = Bexp[(size_t)rfirst * KP1 + 64];
    for (int u = ustart; u <= ue; ++u){
      int r = (T_LEN - 1) - u;
      float bvn = 0.f, b64n = 0.f;
      if (u < ue){
        bvn = Bexp[(size_t)(r - 1) * KP1 + lane]; b64n = Bexp[(size_t)(r - 1) * KP1 + 64];
      }
      float x = bvec * q, x64 = b64 * q64;
      unsigned long long mask = __ballot(x != 0.f);
      float acc = 0.f, acc64 = 0.f;
      while (mask){
        int k = __builtin_ctzll(mask); mask &= mask - 1;
        float xk = readlane_f(x, k);
        acc   = fmaf(xk, Ml[k * 68 + lane], acc);
        acc64 = fmaf(xk, Ml[k * 68 + 64], acc64);
      }
      if (x64 != 0.f){
        acc   = fmaf(x64, Ml[64 * 68 + lane], acc);
        acc64 = fmaf(x64, Ml[64 * 68 + 64], acc64);
      }
      float s = wsum64(acc) + acc64;
      float rr = 1.f / fmaxf(s, 1e-37f);
      q = acc * rr; q64 = acc64 * rr;
      qstore[(size_t)(r - 1) * KP1 + lane] = q;
      if (lane == 0) qstore[(size_t)(r - 1) * KP1 + 64] = q64;
      bvec = bvn; b64 = b64n;
    }
  }
}

// ---------------- prefix over chunk sums + logZ ----------------
__global__ __launch_bounds__(64) void pfx_k(const float* __restrict__ csum,
    float* __restrict__ coff, float* __restrict__ logZ){
  __shared__ float cs[CHK], co[CHK + 1];
  const int lane = threadIdx.x;
  for (int e = lane; e < CHK; e += 64) cs[e] = csum[e];
  __syncthreads();
  if (lane == 0){
    float a = 0.f;
    for (int c = 0; c < CHK; ++c){ co[c] = a; a += cs[c]; }
    co[CHK] = a;
    logZ[0] = a;
  }
  __syncthreads();
  for (int e = lane; e < CHK; e += 64) coff[e] = co[e];
}

__global__ void off_k(float* __restrict__ cfor, const float* __restrict__ coff){
  int t = blockIdx.x * 256 + threadIdx.x;
  if (t >= T_LEN) return;
  int c = (t == 0) ? 0 : (t - 1) / LCH;
  cfor[t] += coff[c];
}

// ---------------- gamma ----------------
__global__ void gamma_k(const float* __restrict__ pstore, const float* __restrict__ qstore,
                        float* __restrict__ gout){
  const int lane = threadIdx.x & 63, w = threadIdx.x >> 6;
  const int t = blockIdx.x * 4 + w;
  if (t >= T_LEN) return;
  float a   = pstore[(size_t)t * KP1 + lane] * qstore[(size_t)t * KP1 + lane];
  float a64 = pstore[(size_t)t * KP1 + 64]   * qstore[(size_t)t * KP1 + 64];
  float s = wsum64(a) + a64;
  float r = rcp_nr(fmaxf(s, 1e-37f));
  gout[(size_t)t * KP1 + lane] = a * r;
  if (lane == 0) gout[(size_t)t * KP1 + 64] = a64 * r;
}

// ---------------- xi: w*exp(u-R) form ----------------
__global__ __launch_bounds__(256) void xi_k(const float* __restrict__ pstore,
                     const float* __restrict__ qstore,
                     const float* __restrict__ logB, const float* __restrict__ cfor,
                     const float* __restrict__ logA_g, const float* __restrict__ logpi,
                     float* __restrict__ xiout){
  const int t = blockIdx.x, tid = threadIdx.x;
  __shared__ float laS[64], bbS[KP1], lpiS[KP1];
  __shared__ float lA[KST * KP1];
  __shared__ float red[4], red2[4];
  for (int e = tid; e < KST * KP1; e += 256) lA[e] = logA_g[e];
  if (tid < 64){
    laS[tid] = logf(pstore[(size_t)t * KP1 + tid]) + cfor[t];
  } else if (tid < 64 + KP1){
    int j = tid - 64;
    bbS[j] = logB[(size_t)(t + 1) * KP1 + j] + logf(qstore[(size_t)(t + 1) * KP1 + j]);
  } else if (tid < 64 + 2 * KP1){
    int j = tid - (64 + KP1);
    lpiS[j] = logpi[j];
  }
  __syncthreads();
  float uu[17], ww[17];
  float um = -3.0e38f;
  #pragma unroll
  for (int r2 = 0; r2 < 17; ++r2){
    int e = tid + 256 * r2;
    if (e < KST * KP1){
      int i = e / KP1;
      int j = e - i * KP1;
      float a = laS[i] + lA[e];
      float b = lpiS[j];
      float mx = fmaxf(a, b), mn = fminf(a, b);
      uu[r2] = bbS[j] + mx;
      ww[r2] = 1.f + expf(mn - mx);
      um = fmaxf(um, uu[r2]);
    } else { uu[r2] = -3.0e38f; ww[r2] = 0.f; }
  }
  um = wmax64(um);
  if ((tid & 63) == 0) red[tid >> 6] = um;
  __syncthreads();
  float R = fmaxf(fmaxf(red[0], red[1]), fmaxf(red[2], red[3]));
  float se = 0.f;
  #pragma unroll
  for (int r2 = 0; r2 < 17; ++r2){
    float e_ = ww[r2] * expf(uu[r2] - R);
    uu[r2] = e_;
    se += e_;
  }
  se = wsum64(se);
  if ((tid & 63) == 0) red2[tid >> 6] = se;
  __syncthreads();
  float Ssum = red2[0] + red2[1] + red2[2] + red2[3];
  float rS = rcp_nr(Ssum);
  float* xrow = xiout + (size_t)t * (KST * KP1);
  #pragma unroll
  for (int r2 = 0; r2 < 17; ++r2){
    int e = tid + 256 * r2;
    if (e < KST * KP1) xrow[e] = uu[r2] * rS;
  }
}

extern "C" void kernel_launch(void* const* d_in, const int* in_sizes, int n_in,
                              void* d_out, int out_size, void* d_ws, size_t ws_size,
                              hipStream_t stream){
  const float* z_mu  = (const float*)d_in[0];
  const float* z_var = (const float*)d_in[1];
  const float* mu    = (const float*)d_in[2];
  const float* kappa = (const float*)d_in[3];
  const float* nu    = (const float*)d_in[4];
  const float* Psi   = (const float*)d_in[5];
  const float* phi   = (const float*)d_in[6];
  const float* pis   = (const float*)d_in[7];
  float* out = (float*)d_out;

  float* ws     = (float*)d_ws;
  float* Lam    = ws;                    // 66560
  float* dLam   = Lam + 66560;           // 2080
  float* constk = dLam + 2080;           // 65
  float* M_mat  = constk + 65;           // 4420
  float* MT     = M_mat + 4420;          // 4420
  float* logA   = MT + 4420;             // 4160
  float* logpi  = logA + 4160;           // 65
  float* logB   = logpi + 65;            // 1,300,000
  float* Bexp   = logB + 1300000;        // 1,300,000
  float* bmax   = Bexp + 1300000;        // 20,000
  float* pstore = bmax + 20000;          // 1,300,000
  float* qstore = pstore + 1300000;      // 1,300,000
  float* cfor   = qstore + 1300000;      // 20,000
  float* S      = cfor + 20000;          // 500*4296 = 2,148,000
  float* Gop    = S + 2148000;           // 50*4296 = 214,800
  float* gseed  = Gop + 214800;          // 50*65 = 3,250
  float* vstore = gseed + 3250;          // 500*65 = 32,500
  float* csum   = vstore + 32500;        // 256
  float* coff   = csum + 256;            // 256

  float* gammaOut = out;
  float* xiOut    = gammaOut + (size_t)T_LEN * KP1;
  float* logZOut  = xiOut + (size_t)(T_LEN - 1) * KST * KP1;

  prep_k<<<KP1, 64, 0, stream>>>(mu, kappa, nu, Psi, Lam, dLam, constk);
  prep_trans<<<1, 64, 0, stream>>>(phi, pis, M_mat, MT, logA, logpi);
  logb_k<<<dim3((T_LEN + 255) / 256, KP1), 256, 0, stream>>>(z_mu, z_var, mu, Lam, dLam, constk, logB);
  bexp_k<<<(T_LEN + 3) / 4, 256, 0, stream>>>(logB, Bexp, bmax);
  p1_k<<<dim3(2 * CHK, 2), 64, 0, stream>>>(MT, Bexp, S);
  p2a_k<<<dim3(NG, 2), 256, 0, stream>>>(S, Gop);
  p2b_k<<<2, 256, 0, stream>>>(Gop, M_mat, Bexp, gseed);
  p2c_k<<<dim3(NG, 2), 256, 0, stream>>>(S, gseed, vstore);
  p3_k<<<dim3(CHK, 2), 64, 0, stream>>>(M_mat, MT, Bexp, bmax, vstore, pstore, qstore, cfor, csum);
  pfx_k<<<1, 64, 0, stream>>>(csum, coff, logZOut);
  off_k<<<(T_LEN + 255) / 256, 256, 0, stream>>>(cfor, coff);
  gamma_k<<<(T_LEN + 3) / 4, 256, 0, stream>>>(pstore, qstore, gammaOut);
  xi_k<<<T_LEN - 1, 256, 0, stream>>>(pstore, qstore, logB, cfor, logA, logpi, xiOut);
}